// Round 16
// baseline (78.173 us; speedup 1.0000x reference)
//
#include <hip/hip_runtime.h>
#include <hip/hip_bf16.h>
#include <stdint.h>

// SmoothLoss: total = (1/24) * sum over 24 offsets of mean( exp(-||dx||^2/200) * ||dy||_1 )
// x = rgb2ycbcr(input) (bias cancels in diffs), y = output. 12 offsets, weight 2x.
// R15 = R11 champion made PERSISTENT: 512 blocks (2/CU), each block loops over
// 4 consecutive row-tiles (identical per-tile phases), removing 6/8 per-CU
// block launch/drain ramps. Everything else byte-identical to R11:
// 512 thr / 8 waves; TH=4 own rows + 2 halo; COLS=520; symmetric all-wave
// gload_lds staging; poisoned halos (plane0=1e19 -> v_exp flushes to 0, no
// bounds checks); Phase B in-place ycbcr with K2=sqrt(0.005/ln2) baked in;
// Phase C windows via ds_read_b128 at 16B lane stride; raw
// __builtin_amdgcn_exp2f; s_setprio around compute clusters.

#define B_ 16
#define H_ 512
#define W_ 512
#define HW_ (H_ * W_)
#define CHW_ (3 * HW_)

#define TH 4          // own rows per tile
#define ROWS 6        // TH + 2 bottom halo
#define COLS 520      // 4 pad | 512 | 4 pad ; img col j <-> lds col j+4
#define NTHREADS 512
#define NTILES 4      // tiles per block (persistent loop)
#define POISON 1e19f
#define K2 0.08493218049364766f  // sqrt(0.005 / ln(2))

__global__ void zero_out_kernel(float* p) { p[0] = 0.0f; }

__device__ __forceinline__ void gload16(const float* gsrc, float* ldst) {
  __builtin_amdgcn_global_load_lds(
      (const __attribute__((address_space(1))) void*)gsrc,
      (__attribute__((address_space(3))) void*)ldst, 16, 0, 0);
}

// O[plane][q]: q <-> img col j0+q (8 floats: own 4 px + 4 right)
template <int DW>
__device__ __forceinline__ float contrib0(const float (&O)[6][8]) {
  const float scale = 2.0f / (24.0f * (float)B_ * (float)H_ * (float)(W_ - DW));
  float s = 0.0f;
#pragma unroll
  for (int p = 0; p < 4; ++p) {
    float d0 = O[0][p] - O[0][p + DW];
    float d1 = O[1][p] - O[1][p + DW];
    float d2 = O[2][p] - O[2][p + DW];
    float nq = -(d0 * d0 + d1 * d1 + d2 * d2);
    float wgt = __builtin_amdgcn_exp2f(nq);   // raw v_exp_f32
    float l1 = fabsf(O[3][p] - O[3][p + DW]) + fabsf(O[4][p] - O[4][p + DW]) +
               fabsf(O[5][p] - O[5][p + DW]);
    s += wgt * l1;
  }
  return scale * s;
}

// N[plane][q]: q <-> img col j0-4+q (12 floats)
template <int DH, int DW>
__device__ __forceinline__ float contribN(const float (&O)[6][8],
                                          const float (&N)[6][12]) {
  constexpr int AW = DW < 0 ? -DW : DW;
  const float scale =
      2.0f / (24.0f * (float)B_ * (float)(H_ - DH) * (float)(W_ - AW));
  float s = 0.0f;
#pragma unroll
  for (int p = 0; p < 4; ++p) {
    const int ni = p + 4 + DW;
    float d0 = O[0][p] - N[0][ni];
    float d1 = O[1][p] - N[1][ni];
    float d2 = O[2][p] - N[2][ni];
    float nq = -(d0 * d0 + d1 * d1 + d2 * d2);
    float wgt = __builtin_amdgcn_exp2f(nq);   // raw v_exp_f32
    float l1 = fabsf(O[3][p] - N[3][ni]) + fabsf(O[4][p] - N[4][ni]) +
               fabsf(O[5][p] - N[5][ni]);
    s += wgt * l1;
  }
  return scale * s;
}

__global__ __launch_bounds__(NTHREADS, 4) void smooth_loss_kernel(
    const float* __restrict__ in, const float* __restrict__ outp,
    float* __restrict__ result) {
  __shared__ alignas(16) float lds[6][ROWS][COLS];  // 74,880 B -> 2 blocks/CU
  __shared__ float wsum[8];

  const int tid = threadIdx.x;
  const int wv = tid >> 6;     // 0..7
  const int lane = tid & 63;
  const int by = blockIdx.x;   // 0..31: tiles 4*by .. 4*by+3
  const int b = blockIdx.y;    // 0..15 batch

  const float* inb = in + (size_t)b * CHW_;
  const float* outb = outp + (size_t)b * CHW_;

  // Phase-C mapping: wave (half,row); lane handles img cols j0..j0+3
  const int half = wv >> 2;
  const int row = wv & 3;
  const int j0 = 256 * half + 4 * lane;

  float acc = 0.0f;

  for (int t = 0; t < NTILES; ++t) {
    const int ibase = (4 * by + t) * TH;

    if (t > 0) __syncthreads();  // Phase C of t-1 done before re-staging

    // ---- Phase A: async stage. 72 wave-chunks = 6 rows x 6 planes x 2 halves ----
#pragma unroll
    for (int k = 0; k < 9; ++k) {
      int wc = wv + 8 * k;            // wave-uniform
      int r = wc / 12;
      int rem = wc - 12 * r;
      int p = rem >> 1;
      int h = rem & 1;
      if (ibase + r < H_) {
        const float* src =
            (p < 3 ? inb + (size_t)p * HW_ : outb + (size_t)(p - 3) * HW_) +
            (size_t)(ibase + r) * W_ + 256 * h + 4 * lane;
        gload16(src, &lds[p][r][4 + 256 * h]);
      }
    }

    // ---- poison halo columns (all rows): plane0 = POISON, others = 0 ----
    if (tid < 288) {
      int p = tid / 48;
      int rem = tid - 48 * p;
      int r = rem >> 3;
      int ci = rem & 7;
      int col = ci < 4 ? ci : 512 + ci;
      lds[p][r][col] = (p == 0) ? POISON : 0.0f;
    }
    // ---- poison out-of-range bottom halo rows (only last tile of image) ----
    if (ibase + TH >= H_) {
      for (int c = tid; c < 6 * 2 * COLS; c += NTHREADS) {
        int p = c / (2 * COLS);
        int rem = c - p * (2 * COLS);
        int r = 4 + rem / COLS;
        int col = rem % COLS;
        lds[p][r][col] = (p == 0) ? POISON : 0.0f;
      }
    }

    __syncthreads();  // drains gload_lds (vmcnt) + ds_writes

    // ---- Phase B: in-place rgb -> ycbcr, coefficients x K2 ----
#pragma unroll
    for (int k = 0; k < 2; ++k) {
      int c = tid + NTHREADS * k;   // 780 float4-items = 6 rows x 130
      if (c < ROWS * 130) {
        int r = c / 130;
        int q4 = c - 130 * r;
        int col = 4 * q4;
        float4 rr = *(const float4*)&lds[0][r][col];
        float4 gg = *(const float4*)&lds[1][r][col];
        float4 bb = *(const float4*)&lds[2][r][col];
        float rv[4] = {rr.x, rr.y, rr.z, rr.w};
        float gv[4] = {gg.x, gg.y, gg.z, gg.w};
        float bv[4] = {bb.x, bb.y, bb.z, bb.w};
        float x0[4], x1[4], x2[4];
#pragma unroll
        for (int m = 0; m < 4; ++m) {
          x0[m] = (0.257f * K2) * rv[m] + (0.564f * K2) * gv[m] + (0.098f * K2) * bv[m];
          x1[m] = (-0.148f * K2) * rv[m] + (-0.291f * K2) * gv[m] + (0.439f * K2) * bv[m];
          x2[m] = (0.439f * K2) * rv[m] + (-0.368f * K2) * gv[m] + (-0.071f * K2) * bv[m];
        }
        *(float4*)&lds[0][r][col] = make_float4(x0[0], x0[1], x0[2], x0[3]);
        *(float4*)&lds[1][r][col] = make_float4(x1[0], x1[1], x1[2], x1[3]);
        *(float4*)&lds[2][r][col] = make_float4(x2[0], x2[1], x2[2], x2[3]);
      }
    }

    __syncthreads();

    // ---- Phase C ----
    float O[6][8];
#pragma unroll
    for (int p6 = 0; p6 < 6; ++p6) {
      *(float4*)&O[p6][0] = *(const float4*)&lds[p6][row][j0 + 4];
      *(float4*)&O[p6][4] = *(const float4*)&lds[p6][row][j0 + 8];
    }

    __builtin_amdgcn_s_setprio(1);
    acc += contrib0<1>(O);
    acc += contrib0<2>(O);
    __builtin_amdgcn_s_setprio(0);

    {
      float N[6][12];
#pragma unroll
      for (int p6 = 0; p6 < 6; ++p6) {
        *(float4*)&N[p6][0] = *(const float4*)&lds[p6][row + 1][j0];
        *(float4*)&N[p6][4] = *(const float4*)&lds[p6][row + 1][j0 + 4];
        *(float4*)&N[p6][8] = *(const float4*)&lds[p6][row + 1][j0 + 8];
      }
      __builtin_amdgcn_s_setprio(1);
      acc += contribN<1, -2>(O, N);
      acc += contribN<1, -1>(O, N);
      acc += contribN<1, 0>(O, N);
      acc += contribN<1, 1>(O, N);
      acc += contribN<1, 2>(O, N);
      __builtin_amdgcn_s_setprio(0);
    }
    {
      float N[6][12];
#pragma unroll
      for (int p6 = 0; p6 < 6; ++p6) {
        *(float4*)&N[p6][0] = *(const float4*)&lds[p6][row + 2][j0];
        *(float4*)&N[p6][4] = *(const float4*)&lds[p6][row + 2][j0 + 4];
        *(float4*)&N[p6][8] = *(const float4*)&lds[p6][row + 2][j0 + 8];
      }
      __builtin_amdgcn_s_setprio(1);
      acc += contribN<2, -2>(O, N);
      acc += contribN<2, -1>(O, N);
      acc += contribN<2, 0>(O, N);
      acc += contribN<2, 1>(O, N);
      acc += contribN<2, 2>(O, N);
      __builtin_amdgcn_s_setprio(0);
    }
  }

  // ---- reduction ----
#pragma unroll
  for (int o = 32; o > 0; o >>= 1) acc += __shfl_down(acc, o, 64);
  if (lane == 0) wsum[wv] = acc;
  __syncthreads();
  if (tid == 0) {
    float s = 0.0f;
#pragma unroll
    for (int wq = 0; wq < 8; ++wq) s += wsum[wq];
    atomicAdd(result, s);
  }
}

extern "C" void kernel_launch(void* const* d_in, const int* in_sizes, int n_in,
                              void* d_out, int out_size, void* d_ws, size_t ws_size,
                              hipStream_t stream) {
  const float* in = (const float*)d_in[0];
  const float* outp = (const float*)d_in[1];
  float* res = (float*)d_out;

  zero_out_kernel<<<1, 1, 0, stream>>>(res);

  dim3 grid(H_ / (TH * NTILES), B_, 1);  // (32, 16) = 512 blocks, 2/CU
  smooth_loss_kernel<<<grid, NTHREADS, 0, stream>>>(in, outp, res);
}

// Round 17
// 49.457 us; speedup vs baseline: 1.5806x; 1.5806x over previous
//
#include <hip/hip_runtime.h>
#include <hip/hip_bf16.h>
#include <stdint.h>

// SmoothLoss: total = (1/24) * sum over 24 offsets of mean( exp(-||dx||^2/200) * ||dy||_1 )
// x = rgb2ycbcr(input) (bias cancels in diffs), y = output. 12 offsets, weight 2x.
// R16 = R11 champion restored verbatim (44.5 us). Ledger of falsified variants:
// R12 TH=2 (+TLP): 69us. R13 packed-f32: scratch spill, 170us. R14 exact-window
// b64 (-25% LDS bytes): neutral. R15 persistent 4-tile loop: 85us (L2 halo
// sharing destroyed, FETCH 2x). R7/R8/R9 restructures: all worse.
// Structure: 512 thr / 8 waves; TH=4 own rows + 2 halo; COLS=520; symmetric
// all-wave gload_lds staging; poisoned halos (plane0=1e19 -> v_exp flushes
// 2^(-2e35) to +0, no bounds checks in hot loop); Phase B in-place ycbcr with
// K2=sqrt(0.005/ln2) baked in; Phase C windows via ds_read_b128 at 16B lane
// stride (conflict-free); raw __builtin_amdgcn_exp2f (v_exp_f32, no libm
// wrapper); s_setprio around compute clusters; LDS 74,880B -> 2 blocks/CU.

#define B_ 16
#define H_ 512
#define W_ 512
#define HW_ (H_ * W_)
#define CHW_ (3 * HW_)

#define TH 4          // own rows per block
#define ROWS 6        // TH + 2 bottom halo
#define COLS 520      // 4 pad | 512 | 4 pad ; img col j <-> lds col j+4
#define NTHREADS 512
#define POISON 1e19f
#define K2 0.08493218049364766f  // sqrt(0.005 / ln(2))

__global__ void zero_out_kernel(float* p) { p[0] = 0.0f; }

__device__ __forceinline__ void gload16(const float* gsrc, float* ldst) {
  __builtin_amdgcn_global_load_lds(
      (const __attribute__((address_space(1))) void*)gsrc,
      (__attribute__((address_space(3))) void*)ldst, 16, 0, 0);
}

// O[plane][q]: q <-> img col j0+q (8 floats: own 4 px + 4 right)
template <int DW>
__device__ __forceinline__ float contrib0(const float (&O)[6][8]) {
  const float scale = 2.0f / (24.0f * (float)B_ * (float)H_ * (float)(W_ - DW));
  float s = 0.0f;
#pragma unroll
  for (int p = 0; p < 4; ++p) {
    float d0 = O[0][p] - O[0][p + DW];
    float d1 = O[1][p] - O[1][p + DW];
    float d2 = O[2][p] - O[2][p + DW];
    float nq = -(d0 * d0 + d1 * d1 + d2 * d2);
    float wgt = __builtin_amdgcn_exp2f(nq);   // raw v_exp_f32
    float l1 = fabsf(O[3][p] - O[3][p + DW]) + fabsf(O[4][p] - O[4][p + DW]) +
               fabsf(O[5][p] - O[5][p + DW]);
    s += wgt * l1;
  }
  return scale * s;
}

// N[plane][q]: q <-> img col j0-4+q (12 floats)
template <int DH, int DW>
__device__ __forceinline__ float contribN(const float (&O)[6][8],
                                          const float (&N)[6][12]) {
  constexpr int AW = DW < 0 ? -DW : DW;
  const float scale =
      2.0f / (24.0f * (float)B_ * (float)(H_ - DH) * (float)(W_ - AW));
  float s = 0.0f;
#pragma unroll
  for (int p = 0; p < 4; ++p) {
    const int ni = p + 4 + DW;
    float d0 = O[0][p] - N[0][ni];
    float d1 = O[1][p] - N[1][ni];
    float d2 = O[2][p] - N[2][ni];
    float nq = -(d0 * d0 + d1 * d1 + d2 * d2);
    float wgt = __builtin_amdgcn_exp2f(nq);   // raw v_exp_f32
    float l1 = fabsf(O[3][p] - N[3][ni]) + fabsf(O[4][p] - N[4][ni]) +
               fabsf(O[5][p] - N[5][ni]);
    s += wgt * l1;
  }
  return scale * s;
}

__global__ __launch_bounds__(NTHREADS, 4) void smooth_loss_kernel(
    const float* __restrict__ in, const float* __restrict__ outp,
    float* __restrict__ result) {
  __shared__ alignas(16) float lds[6][ROWS][COLS];  // 74,880 B
  __shared__ float wsum[8];

  const int tid = threadIdx.x;
  const int wv = tid >> 6;     // 0..7
  const int lane = tid & 63;
  const int by = blockIdx.x;   // 0..127 row tile
  const int b = blockIdx.y;    // 0..15 batch
  const int ibase = by * TH;

  const float* inb = in + (size_t)b * CHW_;
  const float* outb = outp + (size_t)b * CHW_;

  // ---- Phase A: async stage. 72 wave-chunks = 6 rows x 6 planes x 2 halves ----
#pragma unroll
  for (int k = 0; k < 9; ++k) {
    int wc = wv + 8 * k;            // wave-uniform
    int r = wc / 12;
    int rem = wc - 12 * r;
    int p = rem >> 1;
    int h = rem & 1;
    if (ibase + r < H_) {
      const float* src =
          (p < 3 ? inb + (size_t)p * HW_ : outb + (size_t)(p - 3) * HW_) +
          (size_t)(ibase + r) * W_ + 256 * h + 4 * lane;
      gload16(src, &lds[p][r][4 + 256 * h]);
    }
  }

  // ---- poison halo columns (all rows): plane0 = POISON, others = 0 ----
  if (tid < 288) {
    int p = tid / 48;
    int rem = tid - 48 * p;
    int r = rem >> 3;
    int ci = rem & 7;
    int col = ci < 4 ? ci : 512 + ci;
    lds[p][r][col] = (p == 0) ? POISON : 0.0f;
  }
  // ---- poison out-of-range bottom halo rows (only last tile) ----
  if (ibase + TH >= H_) {
    for (int c = tid; c < 6 * 2 * COLS; c += NTHREADS) {
      int p = c / (2 * COLS);
      int rem = c - p * (2 * COLS);
      int r = 4 + rem / COLS;
      int col = rem % COLS;
      lds[p][r][col] = (p == 0) ? POISON : 0.0f;
    }
  }

  __syncthreads();  // drains gload_lds (vmcnt) + ds_writes

  // ---- Phase B: in-place rgb -> ycbcr, coefficients x K2 ----
  {
#pragma unroll
    for (int k = 0; k < 2; ++k) {
      int c = tid + NTHREADS * k;   // 780 float4-items = 6 rows x 130
      if (c < ROWS * 130) {
        int r = c / 130;
        int q4 = c - 130 * r;
        int col = 4 * q4;
        float4 rr = *(const float4*)&lds[0][r][col];
        float4 gg = *(const float4*)&lds[1][r][col];
        float4 bb = *(const float4*)&lds[2][r][col];
        float rv[4] = {rr.x, rr.y, rr.z, rr.w};
        float gv[4] = {gg.x, gg.y, gg.z, gg.w};
        float bv[4] = {bb.x, bb.y, bb.z, bb.w};
        float x0[4], x1[4], x2[4];
#pragma unroll
        for (int m = 0; m < 4; ++m) {
          x0[m] = (0.257f * K2) * rv[m] + (0.564f * K2) * gv[m] + (0.098f * K2) * bv[m];
          x1[m] = (-0.148f * K2) * rv[m] + (-0.291f * K2) * gv[m] + (0.439f * K2) * bv[m];
          x2[m] = (0.439f * K2) * rv[m] + (-0.368f * K2) * gv[m] + (-0.071f * K2) * bv[m];
        }
        *(float4*)&lds[0][r][col] = make_float4(x0[0], x0[1], x0[2], x0[3]);
        *(float4*)&lds[1][r][col] = make_float4(x1[0], x1[1], x1[2], x1[3]);
        *(float4*)&lds[2][r][col] = make_float4(x2[0], x2[1], x2[2], x2[3]);
      }
    }
  }

  __syncthreads();

  // ---- Phase C: wave (half,row); lane handles img cols j0..j0+3 ----
  const int half = wv >> 2;       // 0..1
  const int row = wv & 3;         // own row within tile
  const int j0 = 256 * half + 4 * lane;
  // own img col j <-> lds col j+4; reads at lds cols j0+4, j0+8 (16B lane stride)

  float acc = 0.0f;
  float O[6][8];
#pragma unroll
  for (int p6 = 0; p6 < 6; ++p6) {
    *(float4*)&O[p6][0] = *(const float4*)&lds[p6][row][j0 + 4];
    *(float4*)&O[p6][4] = *(const float4*)&lds[p6][row][j0 + 8];
  }

  __builtin_amdgcn_s_setprio(1);
  acc += contrib0<1>(O);
  acc += contrib0<2>(O);
  __builtin_amdgcn_s_setprio(0);

  {
    float N[6][12];
#pragma unroll
    for (int p6 = 0; p6 < 6; ++p6) {
      *(float4*)&N[p6][0] = *(const float4*)&lds[p6][row + 1][j0];
      *(float4*)&N[p6][4] = *(const float4*)&lds[p6][row + 1][j0 + 4];
      *(float4*)&N[p6][8] = *(const float4*)&lds[p6][row + 1][j0 + 8];
    }
    __builtin_amdgcn_s_setprio(1);
    acc += contribN<1, -2>(O, N);
    acc += contribN<1, -1>(O, N);
    acc += contribN<1, 0>(O, N);
    acc += contribN<1, 1>(O, N);
    acc += contribN<1, 2>(O, N);
    __builtin_amdgcn_s_setprio(0);
  }
  {
    float N[6][12];
#pragma unroll
    for (int p6 = 0; p6 < 6; ++p6) {
      *(float4*)&N[p6][0] = *(const float4*)&lds[p6][row + 2][j0];
      *(float4*)&N[p6][4] = *(const float4*)&lds[p6][row + 2][j0 + 4];
      *(float4*)&N[p6][8] = *(const float4*)&lds[p6][row + 2][j0 + 8];
    }
    __builtin_amdgcn_s_setprio(1);
    acc += contribN<2, -2>(O, N);
    acc += contribN<2, -1>(O, N);
    acc += contribN<2, 0>(O, N);
    acc += contribN<2, 1>(O, N);
    acc += contribN<2, 2>(O, N);
    __builtin_amdgcn_s_setprio(0);
  }

  // ---- reduction ----
#pragma unroll
  for (int o = 32; o > 0; o >>= 1) acc += __shfl_down(acc, o, 64);
  if (lane == 0) wsum[wv] = acc;
  __syncthreads();
  if (tid == 0) {
    float s = 0.0f;
#pragma unroll
    for (int wq = 0; wq < 8; ++wq) s += wsum[wq];
    atomicAdd(result, s);
  }
}

extern "C" void kernel_launch(void* const* d_in, const int* in_sizes, int n_in,
                              void* d_out, int out_size, void* d_ws, size_t ws_size,
                              hipStream_t stream) {
  const float* in = (const float*)d_in[0];
  const float* outp = (const float*)d_in[1];
  float* res = (float*)d_out;

  zero_out_kernel<<<1, 1, 0, stream>>>(res);

  dim3 grid(H_ / TH, B_, 1);  // (128, 16)
  smooth_loss_kernel<<<grid, NTHREADS, 0, stream>>>(in, outp, res);
}

// Round 18
// 48.000 us; speedup vs baseline: 1.6286x; 1.0304x over previous
//
#include <hip/hip_runtime.h>
#include <hip/hip_bf16.h>
#include <stdint.h>

// SmoothLoss: total = (1/24) * sum over 24 offsets of mean( exp(-||dx||^2/200) * ||dy||_1 )
// x = rgb2ycbcr(input) (bias cancels in diffs), y = output. 12 offsets, weight 2x.
// R17 = R11/R16 champion + T1 XCD-chunked blockIdx swizzle (the one untried
// catalog mechanism): 2048 blocks % 8 XCDs == 0 -> bijective chunk remap
// swz = (lin&7)*256 + (lin>>3); each XCD gets 256 CONTIGUOUS row-tiles
// (2 full batch-images), so vertically adjacent tiles' 24KB shared halo rows
// and streaming reuse hit the per-XCD L2 (~200cy) instead of L3 (~600cy),
// shortening the Phase-A barrier drain.
// Everything else byte-identical to R16: 512 thr / 8 waves; TH=4 + 2 halo;
// COLS=520; symmetric all-wave gload_lds staging; poisoned halos (plane0=1e19
// -> v_exp flushes to +0, no bounds checks); Phase B in-place ycbcr with
// K2=sqrt(0.005/ln2) baked in; Phase C ds_read_b128 at 16B lane stride;
// raw __builtin_amdgcn_exp2f; s_setprio; LDS 74,880B -> 2 blocks/CU.

#define B_ 16
#define H_ 512
#define W_ 512
#define HW_ (H_ * W_)
#define CHW_ (3 * HW_)

#define TH 4          // own rows per block
#define ROWS 6        // TH + 2 bottom halo
#define COLS 520      // 4 pad | 512 | 4 pad ; img col j <-> lds col j+4
#define NTHREADS 512
#define POISON 1e19f
#define K2 0.08493218049364766f  // sqrt(0.005 / ln(2))

__global__ void zero_out_kernel(float* p) { p[0] = 0.0f; }

__device__ __forceinline__ void gload16(const float* gsrc, float* ldst) {
  __builtin_amdgcn_global_load_lds(
      (const __attribute__((address_space(1))) void*)gsrc,
      (__attribute__((address_space(3))) void*)ldst, 16, 0, 0);
}

// O[plane][q]: q <-> img col j0+q (8 floats: own 4 px + 4 right)
template <int DW>
__device__ __forceinline__ float contrib0(const float (&O)[6][8]) {
  const float scale = 2.0f / (24.0f * (float)B_ * (float)H_ * (float)(W_ - DW));
  float s = 0.0f;
#pragma unroll
  for (int p = 0; p < 4; ++p) {
    float d0 = O[0][p] - O[0][p + DW];
    float d1 = O[1][p] - O[1][p + DW];
    float d2 = O[2][p] - O[2][p + DW];
    float nq = -(d0 * d0 + d1 * d1 + d2 * d2);
    float wgt = __builtin_amdgcn_exp2f(nq);   // raw v_exp_f32
    float l1 = fabsf(O[3][p] - O[3][p + DW]) + fabsf(O[4][p] - O[4][p + DW]) +
               fabsf(O[5][p] - O[5][p + DW]);
    s += wgt * l1;
  }
  return scale * s;
}

// N[plane][q]: q <-> img col j0-4+q (12 floats)
template <int DH, int DW>
__device__ __forceinline__ float contribN(const float (&O)[6][8],
                                          const float (&N)[6][12]) {
  constexpr int AW = DW < 0 ? -DW : DW;
  const float scale =
      2.0f / (24.0f * (float)B_ * (float)(H_ - DH) * (float)(W_ - AW));
  float s = 0.0f;
#pragma unroll
  for (int p = 0; p < 4; ++p) {
    const int ni = p + 4 + DW;
    float d0 = O[0][p] - N[0][ni];
    float d1 = O[1][p] - N[1][ni];
    float d2 = O[2][p] - N[2][ni];
    float nq = -(d0 * d0 + d1 * d1 + d2 * d2);
    float wgt = __builtin_amdgcn_exp2f(nq);   // raw v_exp_f32
    float l1 = fabsf(O[3][p] - N[3][ni]) + fabsf(O[4][p] - N[4][ni]) +
               fabsf(O[5][p] - N[5][ni]);
    s += wgt * l1;
  }
  return scale * s;
}

__global__ __launch_bounds__(NTHREADS, 4) void smooth_loss_kernel(
    const float* __restrict__ in, const float* __restrict__ outp,
    float* __restrict__ result) {
  __shared__ alignas(16) float lds[6][ROWS][COLS];  // 74,880 B
  __shared__ float wsum[8];

  const int tid = threadIdx.x;
  const int wv = tid >> 6;     // 0..7
  const int lane = tid & 63;

  // ---- T1: XCD-chunked bijective swizzle (2048 blocks, 8 XCDs) ----
  // default: launch-linear i round-robins XCDs (i%8). Remap so XCD k owns
  // contiguous chunk [k*256, (k+1)*256): vertical neighbors stay on one XCD.
  const int lin = blockIdx.x + 128 * blockIdx.y;   // 0..2047
  const int swz = (lin & 7) * 256 + (lin >> 3);    // bijective
  const int by = swz & 127;    // row tile 0..127
  const int b = swz >> 7;      // batch 0..15
  const int ibase = by * TH;

  const float* inb = in + (size_t)b * CHW_;
  const float* outb = outp + (size_t)b * CHW_;

  // ---- Phase A: async stage. 72 wave-chunks = 6 rows x 6 planes x 2 halves ----
#pragma unroll
  for (int k = 0; k < 9; ++k) {
    int wc = wv + 8 * k;            // wave-uniform
    int r = wc / 12;
    int rem = wc - 12 * r;
    int p = rem >> 1;
    int h = rem & 1;
    if (ibase + r < H_) {
      const float* src =
          (p < 3 ? inb + (size_t)p * HW_ : outb + (size_t)(p - 3) * HW_) +
          (size_t)(ibase + r) * W_ + 256 * h + 4 * lane;
      gload16(src, &lds[p][r][4 + 256 * h]);
    }
  }

  // ---- poison halo columns (all rows): plane0 = POISON, others = 0 ----
  if (tid < 288) {
    int p = tid / 48;
    int rem = tid - 48 * p;
    int r = rem >> 3;
    int ci = rem & 7;
    int col = ci < 4 ? ci : 512 + ci;
    lds[p][r][col] = (p == 0) ? POISON : 0.0f;
  }
  // ---- poison out-of-range bottom halo rows (only last tile) ----
  if (ibase + TH >= H_) {
    for (int c = tid; c < 6 * 2 * COLS; c += NTHREADS) {
      int p = c / (2 * COLS);
      int rem = c - p * (2 * COLS);
      int r = 4 + rem / COLS;
      int col = rem % COLS;
      lds[p][r][col] = (p == 0) ? POISON : 0.0f;
    }
  }

  __syncthreads();  // drains gload_lds (vmcnt) + ds_writes

  // ---- Phase B: in-place rgb -> ycbcr, coefficients x K2 ----
  {
#pragma unroll
    for (int k = 0; k < 2; ++k) {
      int c = tid + NTHREADS * k;   // 780 float4-items = 6 rows x 130
      if (c < ROWS * 130) {
        int r = c / 130;
        int q4 = c - 130 * r;
        int col = 4 * q4;
        float4 rr = *(const float4*)&lds[0][r][col];
        float4 gg = *(const float4*)&lds[1][r][col];
        float4 bb = *(const float4*)&lds[2][r][col];
        float rv[4] = {rr.x, rr.y, rr.z, rr.w};
        float gv[4] = {gg.x, gg.y, gg.z, gg.w};
        float bv[4] = {bb.x, bb.y, bb.z, bb.w};
        float x0[4], x1[4], x2[4];
#pragma unroll
        for (int m = 0; m < 4; ++m) {
          x0[m] = (0.257f * K2) * rv[m] + (0.564f * K2) * gv[m] + (0.098f * K2) * bv[m];
          x1[m] = (-0.148f * K2) * rv[m] + (-0.291f * K2) * gv[m] + (0.439f * K2) * bv[m];
          x2[m] = (0.439f * K2) * rv[m] + (-0.368f * K2) * gv[m] + (-0.071f * K2) * bv[m];
        }
        *(float4*)&lds[0][r][col] = make_float4(x0[0], x0[1], x0[2], x0[3]);
        *(float4*)&lds[1][r][col] = make_float4(x1[0], x1[1], x1[2], x1[3]);
        *(float4*)&lds[2][r][col] = make_float4(x2[0], x2[1], x2[2], x2[3]);
      }
    }
  }

  __syncthreads();

  // ---- Phase C: wave (half,row); lane handles img cols j0..j0+3 ----
  const int half = wv >> 2;       // 0..1
  const int row = wv & 3;         // own row within tile
  const int j0 = 256 * half + 4 * lane;
  // own img col j <-> lds col j+4; reads at lds cols j0+4, j0+8 (16B lane stride)

  float acc = 0.0f;
  float O[6][8];
#pragma unroll
  for (int p6 = 0; p6 < 6; ++p6) {
    *(float4*)&O[p6][0] = *(const float4*)&lds[p6][row][j0 + 4];
    *(float4*)&O[p6][4] = *(const float4*)&lds[p6][row][j0 + 8];
  }

  __builtin_amdgcn_s_setprio(1);
  acc += contrib0<1>(O);
  acc += contrib0<2>(O);
  __builtin_amdgcn_s_setprio(0);

  {
    float N[6][12];
#pragma unroll
    for (int p6 = 0; p6 < 6; ++p6) {
      *(float4*)&N[p6][0] = *(const float4*)&lds[p6][row + 1][j0];
      *(float4*)&N[p6][4] = *(const float4*)&lds[p6][row + 1][j0 + 4];
      *(float4*)&N[p6][8] = *(const float4*)&lds[p6][row + 1][j0 + 8];
    }
    __builtin_amdgcn_s_setprio(1);
    acc += contribN<1, -2>(O, N);
    acc += contribN<1, -1>(O, N);
    acc += contribN<1, 0>(O, N);
    acc += contribN<1, 1>(O, N);
    acc += contribN<1, 2>(O, N);
    __builtin_amdgcn_s_setprio(0);
  }
  {
    float N[6][12];
#pragma unroll
    for (int p6 = 0; p6 < 6; ++p6) {
      *(float4*)&N[p6][0] = *(const float4*)&lds[p6][row + 2][j0];
      *(float4*)&N[p6][4] = *(const float4*)&lds[p6][row + 2][j0 + 4];
      *(float4*)&N[p6][8] = *(const float4*)&lds[p6][row + 2][j0 + 8];
    }
    __builtin_amdgcn_s_setprio(1);
    acc += contribN<2, -2>(O, N);
    acc += contribN<2, -1>(O, N);
    acc += contribN<2, 0>(O, N);
    acc += contribN<2, 1>(O, N);
    acc += contribN<2, 2>(O, N);
    __builtin_amdgcn_s_setprio(0);
  }

  // ---- reduction ----
#pragma unroll
  for (int o = 32; o > 0; o >>= 1) acc += __shfl_down(acc, o, 64);
  if (lane == 0) wsum[wv] = acc;
  __syncthreads();
  if (tid == 0) {
    float s = 0.0f;
#pragma unroll
    for (int wq = 0; wq < 8; ++wq) s += wsum[wq];
    atomicAdd(result, s);
  }
}

extern "C" void kernel_launch(void* const* d_in, const int* in_sizes, int n_in,
                              void* d_out, int out_size, void* d_ws, size_t ws_size,
                              hipStream_t stream) {
  const float* in = (const float*)d_in[0];
  const float* outp = (const float*)d_in[1];
  float* res = (float*)d_out;

  zero_out_kernel<<<1, 1, 0, stream>>>(res);

  dim3 grid(H_ / TH, B_, 1);  // (128, 16) = 2048 blocks
  smooth_loss_kernel<<<grid, NTHREADS, 0, stream>>>(in, outp, res);
}